// Round 6
// baseline (493.920 us; speedup 1.0000x reference)
//
#include <hip/hip_runtime.h>
#include <stdint.h>

// Problem constants (from reference)
#define HH 176
#define WW 200
#define BB 4
#define CIN 128
#define COUT 256
#define NPTS (4096 * 64)            // 262144 points
#define CELLS (BB * WW * HH)        // 140800 cells = 2200 * 64
#define FEAT_OUT_ELEMS ((size_t)NPTS * COUT)  // 67108864
#define CAP 32                      // max points/cell tracked (Poisson lambda~1.6 -> max ~12)
#define WCELLS 16                   // cells per WAVE (one full MFMA N-tile)
#define LDSWN 136                   // normed ushort stride (16B-aligned b128 frag reads)
#define LDSWO 264                   // out16 ushort stride (8B-aligned ushort4 rows)

typedef __attribute__((ext_vector_type(8))) short bf16x8;
typedef __attribute__((ext_vector_type(4))) float f32x4;

// ---------- bf16 helpers (RNE) ----------
__device__ __forceinline__ unsigned short f2bf(float f) {
    union { float f; unsigned int u; } c; c.f = f;
    unsigned int u = c.u;
    u += 0x7fffu + ((u >> 16) & 1u);
    return (unsigned short)(u >> 16);
}
__device__ __forceinline__ float bf2f(unsigned int h16) {
    union { unsigned int u; float f; } c; c.u = h16 << 16;
    return c.f;
}

// ---------- 0. prep: zero counts + convert W to bf16 ----------
__global__ __launch_bounds__(256) void prep_kernel(
    const float* __restrict__ lw, unsigned short* __restrict__ wb,
    int* __restrict__ counts)
{
    int i = blockIdx.x * 256 + threadIdx.x;   // grid 550 -> i < 140800
    if (i < COUT * CIN) wb[i] = f2bf(lw[i]);
    counts[i] = 0;
}

// ---------- 1. build: per-cell lists + index echo + zero invalid output rows ----------
__global__ __launch_bounds__(256) void build_kernel(
    const int* __restrict__ idx, int* __restrict__ counts, int* __restrict__ plist,
    float* __restrict__ out_idx, float* __restrict__ out_feats)
{
    __shared__ unsigned char validf[256];
    int tid = threadIdx.x;
    int p0 = blockIdx.x * 256;
    int p = p0 + tid;
    int b = idx[3 * p], x = idx[3 * p + 1], y = idx[3 * p + 2];
    out_idx[3 * p]     = (float)b;
    out_idx[3 * p + 1] = (float)x;
    out_idx[3 * p + 2] = (float)y;
    bool valid = ((unsigned)x < HH && (unsigned)y < WW);
    validf[tid] = valid ? 1 : 0;
    if (valid) {
        int cell = (b * WW + y) * HH + x;
        int slot = atomicAdd(&counts[cell], 1);
        if (slot < CAP) plist[(size_t)cell * CAP + slot] = p;
    }
    __syncthreads();
    // cooperatively zero the 256-ch output rows of this block's invalid points
    int w = tid >> 6, lane = tid & 63;
    float4 z = { 0.0f, 0.0f, 0.0f, 0.0f };
    for (int v = w; v < 256; v += 4)
        if (!validf[v])
            *(float4*)(out_feats + (size_t)(p0 + v) * COUT + lane * 4) = z;
}

// ---------- 2. fused v4: WAVE-AUTONOMOUS accumulate + LN + MFMA + scatter ----------
// Each wave owns one 16-cell MFMA N-tile end to end; ZERO __syncthreads.
// counts/plist read via wave-uniform (scalar) addressing; feats-row loads are
// fully independent; normed staged in wave-private LDS; all 4 B-frags pulled
// to registers so the buffer is reused for the transposed out tile; scatter
// uses register-held pids. LDS 8.4 KB/wave -> 4 blocks/CU (16 waves).
__global__ __launch_bounds__(256) void fused_kernel(
    const float* __restrict__ feats,
    const unsigned short* __restrict__ Wb,   // [256][128] bf16
    const int* __restrict__ counts,
    const int* __restrict__ plist,
    const float* __restrict__ nw, const float* __restrict__ nb,
    float* __restrict__ out)                 // [NPTS][256] f32
{
    __shared__ unsigned short stage[4][WCELLS * LDSWO];   // 4 x 8448 B, wave-private

    int tid = threadIdx.x;
    int w = tid >> 6, lane = tid & 63;
    int l15 = lane & 15, g = lane >> 4;
    int kgrp = g * 8, orow = g * 4;
    int c0 = blockIdx.x * 64 + w * WCELLS;   // this wave's 16 cells
    unsigned short* buf = &stage[w][0];

    float w0 = nw[lane * 2], w1 = nw[lane * 2 + 1];
    float b0 = nb[lane * 2], b1 = nb[lane * 2 + 1];

    // wave-uniform metadata: 16 counts + 16 pid-quads (scalar loads)
    int cnts[WCELLS];
    int4 pq[WCELLS];
    #pragma unroll
    for (int c = 0; c < WCELLS; ++c) {
        int n = counts[c0 + c];
        cnts[c] = n < CAP ? n : CAP;
        pq[c] = *(const int4*)(plist + (size_t)(c0 + c) * CAP);
    }

    // ---- accumulate + LN per cell (independent loads; wave-uniform guards) ----
    #pragma unroll
    for (int c = 0; c < WCELLS; ++c) {
        int cnt = cnts[c];
        float s0 = 0.0f, s1 = 0.0f;
        if (cnt > 0) { float2 t = *(const float2*)(feats + (size_t)pq[c].x * CIN + lane * 2); s0 += t.x; s1 += t.y; }
        if (cnt > 1) { float2 t = *(const float2*)(feats + (size_t)pq[c].y * CIN + lane * 2); s0 += t.x; s1 += t.y; }
        if (cnt > 2) { float2 t = *(const float2*)(feats + (size_t)pq[c].z * CIN + lane * 2); s0 += t.x; s1 += t.y; }
        if (cnt > 3) { float2 t = *(const float2*)(feats + (size_t)pq[c].w * CIN + lane * 2); s0 += t.x; s1 += t.y; }
        if (cnt > 4) {                       // rare (~2% of cells), wave-uniform
            for (int s = 4; s < cnt; ++s) {
                int pid = plist[(size_t)(c0 + c) * CAP + s];
                float2 t = *(const float2*)(feats + (size_t)pid * CIN + lane * 2);
                s0 += t.x; s1 += t.y;
            }
        }
        float s = s0 + s1, ss = s0 * s0 + s1 * s1;
        #pragma unroll
        for (int m = 32; m >= 1; m >>= 1) {
            s  += __shfl_xor(s, m, 64);
            ss += __shfl_xor(ss, m, 64);
        }
        float mu  = s * (1.0f / 128.0f);
        float var = ss * (1.0f / 128.0f) - mu * mu;
        float inv = rsqrtf(var + 1e-5f);
        ushort2 st;
        st.x = f2bf((s0 - mu) * inv * w0 + b0);
        st.y = f2bf((s1 - mu) * inv * w1 + b1);
        *(ushort2*)(&buf[c * LDSWN + lane * 2]) = st;
    }

    // ---- pull all B-frags to registers (frees buf for the out tile) ----
    // B layout: col = l15 (cell), k = kgrp + kk*32 .. +8
    bf16x8 bfr[4];
    #pragma unroll
    for (int kk = 0; kk < 4; ++kk)
        bfr[kk] = *(const bf16x8*)(&buf[l15 * LDSWN + kgrp + kk * 32]);

    // ---- MFMA: 16 o-tiles x 4 K-steps; A-frags from L2-hot Wb ----
    #pragma unroll
    for (int i = 0; i < 16; ++i) {
        f32x4 acc = (f32x4){0.0f, 0.0f, 0.0f, 0.0f};
        #pragma unroll
        for (int kk = 0; kk < 4; ++kk) {
            bf16x8 av = *(const bf16x8*)(Wb + (size_t)((i * 16 + l15) * CIN) + kgrp + kk * 32);
            acc = __builtin_amdgcn_mfma_f32_16x16x32_bf16(av, bfr[kk], acc, 0, 0, 0);
        }
        // C/D layout: col(cell)=l15, row(o)=g*4+reg -> transpose into buf
        ushort4 st;
        st.x = f2bf(acc[0]);
        st.y = f2bf(acc[1]);
        st.z = f2bf(acc[2]);
        st.w = f2bf(acc[3]);
        *(ushort4*)(&buf[l15 * LDSWO + i * 16 + orow]) = st;
    }

    // ---- scatter: this wave's own points, full 1 KB row per point ----
    #pragma unroll
    for (int c = 0; c < WCELLS; ++c) {
        int cnt = cnts[c];
        if (cnt > 0) {
            ushort4 v = *(const ushort4*)(&buf[c * LDSWO + lane * 4]);
            float4 o4;
            o4.x = bf2f(v.x);
            o4.y = bf2f(v.y);
            o4.z = bf2f(v.z);
            o4.w = bf2f(v.w);
            *(float4*)(out + (size_t)pq[c].x * COUT + lane * 4) = o4;
            if (cnt > 1) *(float4*)(out + (size_t)pq[c].y * COUT + lane * 4) = o4;
            if (cnt > 2) *(float4*)(out + (size_t)pq[c].z * COUT + lane * 4) = o4;
            if (cnt > 3) *(float4*)(out + (size_t)pq[c].w * COUT + lane * 4) = o4;
            if (cnt > 4) {                   // rare tail
                for (int s = 4; s < cnt; ++s) {
                    int pid = plist[(size_t)(c0 + c) * CAP + s];
                    *(float4*)(out + (size_t)pid * COUT + lane * 4) = o4;
                }
            }
        }
    }
}

extern "C" void kernel_launch(void* const* d_in, const int* in_sizes, int n_in,
                              void* d_out, int out_size, void* d_ws, size_t ws_size,
                              hipStream_t stream)
{
    const float* feats = (const float*)d_in[0];
    const int*   idx   = (const int*)d_in[1];
    const float* nw    = (const float*)d_in[2];
    const float* nb    = (const float*)d_in[3];
    const float* lw    = (const float*)d_in[4];
    float* out = (float*)d_out;

    char* ws = (char*)d_ws;
    int* counts = (int*)ws;                                        // 0.56 MB
    int* plist  = (int*)(ws + (1u << 20));                         // 18 MB
    unsigned short* wb     = (unsigned short*)(ws + (20u << 20));  // 64 KB bf16

    prep_kernel<<<CELLS / 256, 256, 0, stream>>>(lw, wb, counts);
    build_kernel<<<NPTS / 256, 256, 0, stream>>>(idx, counts, plist, out + FEAT_OUT_ELEMS, out);
    fused_kernel<<<CELLS / 64, 256, 0, stream>>>(feats, wb, counts, plist, nw, nb, out);
}

// Round 7
// 477.782 us; speedup vs baseline: 1.0338x; 1.0338x over previous
//
#include <hip/hip_runtime.h>
#include <stdint.h>

// Problem constants (from reference)
#define HH 176
#define WW 200
#define BB 4
#define CIN 128
#define COUT 256
#define NPTS (4096 * 64)            // 262144 points
#define CELLS (BB * WW * HH)        // 140800 cells = 8800 * 16
#define FEAT_OUT_ELEMS ((size_t)NPTS * COUT)  // 67108864
#define CAP 32                      // max points/cell tracked (Poisson lambda~1.6 -> max ~12)
#define BCELLS 16                   // cells per BLOCK (one MFMA N-tile), 4 waves
#define LDSWN 132                   // normed ushort stride (R5-measured conflict-clean)
#define LDSWO 260                   // out16 ushort stride (R5-measured conflict-clean)

typedef __attribute__((ext_vector_type(8))) short bf16x8;
typedef __attribute__((ext_vector_type(4))) float f32x4;

// ---------- bf16 helpers (RNE) ----------
__device__ __forceinline__ unsigned short f2bf(float f) {
    union { float f; unsigned int u; } c; c.f = f;
    unsigned int u = c.u;
    u += 0x7fffu + ((u >> 16) & 1u);
    return (unsigned short)(u >> 16);
}
__device__ __forceinline__ float bf2f(unsigned int h16) {
    union { unsigned int u; float f; } c; c.u = h16 << 16;
    return c.f;
}

// ---------- 0. prep: zero counts + convert W to bf16 ----------
__global__ __launch_bounds__(256) void prep_kernel(
    const float* __restrict__ lw, unsigned short* __restrict__ wb,
    int* __restrict__ counts)
{
    int i = blockIdx.x * 256 + threadIdx.x;   // grid 550 -> i < 140800
    if (i < COUT * CIN) wb[i] = f2bf(lw[i]);
    counts[i] = 0;
}

// ---------- 1. build: per-cell lists + index echo + zero invalid output rows ----------
__global__ __launch_bounds__(256) void build_kernel(
    const int* __restrict__ idx, int* __restrict__ counts, int* __restrict__ plist,
    float* __restrict__ out_idx, float* __restrict__ out_feats)
{
    __shared__ unsigned char validf[256];
    int tid = threadIdx.x;
    int p0 = blockIdx.x * 256;
    int p = p0 + tid;
    int b = idx[3 * p], x = idx[3 * p + 1], y = idx[3 * p + 2];
    out_idx[3 * p]     = (float)b;
    out_idx[3 * p + 1] = (float)x;
    out_idx[3 * p + 2] = (float)y;
    bool valid = ((unsigned)x < HH && (unsigned)y < WW);
    validf[tid] = valid ? 1 : 0;
    if (valid) {
        int cell = (b * WW + y) * HH + x;
        int slot = atomicAdd(&counts[cell], 1);
        if (slot < CAP) plist[(size_t)cell * CAP + slot] = p;
    }
    __syncthreads();
    // cooperatively zero the 256-ch output rows of this block's invalid points
    int w = tid >> 6, lane = tid & 63;
    float4 z = { 0.0f, 0.0f, 0.0f, 0.0f };
    for (int v = w; v < 256; v += 4)
        if (!validf[v])
            *(float4*)(out_feats + (size_t)(p0 + v) * COUT + lane * 4) = z;
}

// ---------- 2. fused v5: 16-cell blocks, 4 waves, 2 thin barriers ----------
// 8800 blocks (2x R5's wave count, half the per-wave serial work). Wave w:
// accumulate cells {4w..4w+3} (<=16 independent feats-row loads, pq in 16 VGPR)
// + in-register LN -> normedl; barrier; MFMA over the shared 16-cell tile,
// wave w owns o-band [64w,64w+64) (16 MFMAs, A-frags from L2-hot Wb);
// transpose to out16; barrier; scatter own 4 cells from register pids.
// LDS 12.5 KB -> 8 blocks/CU (100% wave cap).
__global__ __launch_bounds__(256) void fused_kernel(
    const float* __restrict__ feats,
    const unsigned short* __restrict__ Wb,   // [256][128] bf16
    const int* __restrict__ counts,
    const int* __restrict__ plist,
    const float* __restrict__ nw, const float* __restrict__ nb,
    float* __restrict__ out)                 // [NPTS][256] f32
{
    __shared__ unsigned short normedl[BCELLS * LDSWN];  // 4224 B
    __shared__ unsigned short out16[BCELLS * LDSWO];    // 8320 B

    int tid = threadIdx.x;
    int w = tid >> 6, lane = tid & 63;
    int l15 = lane & 15, g = lane >> 4;
    int kgrp = g * 8, orow = g * 4;
    int c0 = blockIdx.x * BCELLS;
    int cw0 = c0 + w * 4;                    // this wave's 4 cells

    float w0 = nw[lane * 2], w1 = nw[lane * 2 + 1];
    float b0 = nb[lane * 2], b1 = nb[lane * 2 + 1];

    // wave metadata: 4 counts + 4 pid-quads (independent loads)
    int cnts[4];
    int4 pq[4];
    #pragma unroll
    for (int ci = 0; ci < 4; ++ci) {
        int n = counts[cw0 + ci];
        cnts[ci] = n < CAP ? n : CAP;
        pq[ci] = *(const int4*)(plist + (size_t)(cw0 + ci) * CAP);
    }

    // ---- accumulate + LN per cell (loads independent across cells) ----
    #pragma unroll
    for (int ci = 0; ci < 4; ++ci) {
        int cnt = cnts[ci];
        float s0 = 0.0f, s1 = 0.0f;
        if (cnt > 0) { float2 t = *(const float2*)(feats + (size_t)pq[ci].x * CIN + lane * 2); s0 += t.x; s1 += t.y; }
        if (cnt > 1) { float2 t = *(const float2*)(feats + (size_t)pq[ci].y * CIN + lane * 2); s0 += t.x; s1 += t.y; }
        if (cnt > 2) { float2 t = *(const float2*)(feats + (size_t)pq[ci].z * CIN + lane * 2); s0 += t.x; s1 += t.y; }
        if (cnt > 3) { float2 t = *(const float2*)(feats + (size_t)pq[ci].w * CIN + lane * 2); s0 += t.x; s1 += t.y; }
        if (cnt > 4) {                       // rare (~2% of cells), wave-uniform
            for (int s = 4; s < cnt; ++s) {
                int pid = plist[(size_t)(cw0 + ci) * CAP + s];
                float2 t = *(const float2*)(feats + (size_t)pid * CIN + lane * 2);
                s0 += t.x; s1 += t.y;
            }
        }
        float s = s0 + s1, ss = s0 * s0 + s1 * s1;
        #pragma unroll
        for (int m = 32; m >= 1; m >>= 1) {
            s  += __shfl_xor(s, m, 64);
            ss += __shfl_xor(ss, m, 64);
        }
        float mu  = s * (1.0f / 128.0f);
        float var = ss * (1.0f / 128.0f) - mu * mu;
        float inv = rsqrtf(var + 1e-5f);
        ushort2 st;
        st.x = f2bf((s0 - mu) * inv * w0 + b0);
        st.y = f2bf((s1 - mu) * inv * w1 + b1);
        *(ushort2*)(&normedl[(w * 4 + ci) * LDSWN + lane * 2]) = st;
    }
    __syncthreads();   // #1: normedl ready (parks only 4 waves, phases are thin)

    // ---- MFMA: B-frags once; wave w owns o-band [64w, 64w+64) = 4 o-tiles ----
    bf16x8 bfr[4];
    #pragma unroll
    for (int kk = 0; kk < 4; ++kk)
        bfr[kk] = *(const bf16x8*)(&normedl[l15 * LDSWN + kgrp + kk * 32]);

    #pragma unroll
    for (int i = 0; i < 4; ++i) {
        f32x4 acc = (f32x4){0.0f, 0.0f, 0.0f, 0.0f};
        #pragma unroll
        for (int kk = 0; kk < 4; ++kk) {
            bf16x8 av = *(const bf16x8*)(Wb + (size_t)((w * 64 + i * 16 + l15) * CIN) + kgrp + kk * 32);
            acc = __builtin_amdgcn_mfma_f32_16x16x32_bf16(av, bfr[kk], acc, 0, 0, 0);
        }
        // C/D layout: col(cell)=l15, row(o)=g*4+reg -> transpose into out16
        ushort4 st;
        st.x = f2bf(acc[0]);
        st.y = f2bf(acc[1]);
        st.z = f2bf(acc[2]);
        st.w = f2bf(acc[3]);
        *(ushort4*)(&out16[l15 * LDSWO + w * 64 + i * 16 + orow]) = st;
    }
    __syncthreads();   // #2: out16 ready

    // ---- scatter: own 4 cells, full 1 KB row per point, pids from registers ----
    #pragma unroll
    for (int ci = 0; ci < 4; ++ci) {
        int cnt = cnts[ci];
        if (cnt > 0) {
            ushort4 v = *(const ushort4*)(&out16[(w * 4 + ci) * LDSWO + lane * 4]);
            float4 o4;
            o4.x = bf2f(v.x);
            o4.y = bf2f(v.y);
            o4.z = bf2f(v.z);
            o4.w = bf2f(v.w);
            *(float4*)(out + (size_t)pq[ci].x * COUT + lane * 4) = o4;
            if (cnt > 1) *(float4*)(out + (size_t)pq[ci].y * COUT + lane * 4) = o4;
            if (cnt > 2) *(float4*)(out + (size_t)pq[ci].z * COUT + lane * 4) = o4;
            if (cnt > 3) *(float4*)(out + (size_t)pq[ci].w * COUT + lane * 4) = o4;
            if (cnt > 4) {                   // rare tail
                for (int s = 4; s < cnt; ++s) {
                    int pid = plist[(size_t)(cw0 + ci) * CAP + s];
                    *(float4*)(out + (size_t)pid * COUT + lane * 4) = o4;
                }
            }
        }
    }
}

extern "C" void kernel_launch(void* const* d_in, const int* in_sizes, int n_in,
                              void* d_out, int out_size, void* d_ws, size_t ws_size,
                              hipStream_t stream)
{
    const float* feats = (const float*)d_in[0];
    const int*   idx   = (const int*)d_in[1];
    const float* nw    = (const float*)d_in[2];
    const float* nb    = (const float*)d_in[3];
    const float* lw    = (const float*)d_in[4];
    float* out = (float*)d_out;

    char* ws = (char*)d_ws;
    int* counts = (int*)ws;                                        // 0.56 MB
    int* plist  = (int*)(ws + (1u << 20));                         // 18 MB
    unsigned short* wb     = (unsigned short*)(ws + (20u << 20));  // 64 KB bf16

    prep_kernel<<<CELLS / 256, 256, 0, stream>>>(lw, wb, counts);
    build_kernel<<<NPTS / 256, 256, 0, stream>>>(idx, counts, plist, out + FEAT_OUT_ELEMS, out);
    fused_kernel<<<CELLS / BCELLS, 256, 0, stream>>>(feats, wb, counts, plist, nw, nb, out);
}